// Round 7
// baseline (144.504 us; speedup 1.0000x reference)
//
#include <hip/hip_runtime.h>

// SingleStageDetector fused head+IoU, R7. f32 I/O; both GEMMs via bf16 MFMA.
// R7: prep_all builds (a) B-fragment-ready transposed-F image gBf, (b) W1
// frag image, (c) W2 frag image. gemm1_partial is then LDS-free/barrier-free
// in its K-loop: A and B frags both via coalesced global_load_dwordx4
// (1 KB/wave-instr) from L2/L3-resident ws images, pipelined 1 step ahead.

#define CIN_  1280
#define HW_   49
#define HID_  128
#define OUTD_ 65
#define NGT_  40
#define NP_   441

// flat output offsets (elements), reference return order
#define CONF_OFF 0
#define OFFS_OFF 112896   // 256*9*49
#define CLS_OFF  564480   // + 256*9*4*49
#define IOU_OFF  815360   // + 256*20*49 ; total 5,331,200

// workspace layout (u32 units)
#define WS_W1F   0u         // 81920 u32: W1 frags ((K32*8+mt)*64+lane)*4+sub
#define WS_W2F   81920u     // 5120 u32:  W2 frags ((ks2*5+mt2)*64+lane)*4+sub
#define WS_PART  87040u     // 256*4*64*49 = 3,211,264 u32 bf16-pair partials
#define WS_BF    3298304u   // 256*40960 = 10,485,760 u32 F-frag image (40 MB)
#define WS_NEED_FULL ((3298304u + 10485760u) * 4u)   // 55,136,256 B
#define WS_NEED_MID  (81920u * 4u)

typedef __bf16 bf16x8 __attribute__((ext_vector_type(8)));
typedef float  f32x4  __attribute__((ext_vector_type(4)));

__device__ __forceinline__ unsigned pack2bf(float lo, float hi) {
    unsigned a = __float_as_uint(lo);
    unsigned b = __float_as_uint(hi);
    a = (a + 0x7FFFu + ((a >> 16) & 1u)) >> 16;   // RNE f32->bf16
    b = (b + 0x7FFFu + ((b >> 16) & 1u)) >> 16;
    return a | (b << 16);
}
__device__ __forceinline__ float bflo(unsigned u) { return __uint_as_float(u << 16); }
__device__ __forceinline__ float bfhi(unsigned u) { return __uint_as_float(u & 0xFFFF0000u); }
__device__ __forceinline__ float sigmoidf_(float v) { return 1.f / (1.f + __expf(-v)); }

__device__ __forceinline__ bf16x8 ld_frag(const unsigned* p) {
    union { uint4 u; bf16x8 v; } x;
    x.u = *(const uint4*)p;
    return x.v;
}
__device__ __forceinline__ bf16x8 as_bf(uint4 u) {
    union { uint4 u; bf16x8 v; } x; x.u = u; return x.v;
}

// ---------------------------------------------------------------------------
// prep_all: block-range dispatch.
//   blk <  5120: transpose F chunk (b = blk/20, ck = blk%20, 64 channels):
//                coalesced float4 read -> LDS [64][52] -> frag-order bf16 image
//                gBf[b*40960 + (K32*4+nt)*256 + lane*4 + sub], K32 = 2ck+{0,1}.
//                nt=3 rows baked with the duplicate-row trick (m16==0 -> hw48).
//   blk <  5440: W1 frag image (X = (blk-5120)*256+tid over 81920 words).
//   else      : W2 frag image (20 blocks, 5120 words), rows >=65 zeroed.
// ---------------------------------------------------------------------------
__global__ __launch_bounds__(256) void prep_all(
    const float* __restrict__ F, const float* __restrict__ W1,
    const float* __restrict__ W2, unsigned* __restrict__ ws)
{
    __shared__ float smT[64 * 52];      // 13,312 B
    const int tid = threadIdx.x;
    const int blk = blockIdx.x;

    if (blk < 5120) {
        const int b  = blk / 20;
        const int ck = blk - b * 20;
        const float4* src = (const float4*)(F + b * 62720 + ck * 3136);
        for (int i = tid; i < 784; i += 256) {
            float4 v = src[i];
            int fl = i * 4;
            int c0 = fl / 49, h0 = fl - c0 * 49;
            smT[c0 * 52 + h0] = v.x;
            int f1 = fl + 1; int c1 = f1 / 49, h1 = f1 - c1 * 49;
            smT[c1 * 52 + h1] = v.y;
            int f2 = fl + 2; int c2 = f2 / 49, h2 = f2 - c2 * 49;
            smT[c2 * 52 + h2] = v.z;
            int f3 = fl + 3; int c3 = f3 / 49, h3 = f3 - c3 * 49;
            smT[c3 * 52 + h3] = v.w;
        }
        __syncthreads();
        unsigned* gBf = ws + WS_BF + b * 40960u + ck * 2048u;
        #pragma unroll
        for (int r = 0; r < 8; ++r) {
            int X = r * 256 + tid;                 // 0..2047
            int sub  = X & 3;
            int lane = (X >> 2) & 63;
            int fi   = X >> 8;                     // 0..7
            int nt = fi & 3, kl = fi >> 2;         // kl in {0,1}
            int m16l = lane & 15, quadl = lane >> 4;
            int hw = (nt < 3) ? (nt * 16 + m16l)
                              : ((m16l == 0) ? 48 : (m16l - 1));
            int c = kl * 32 + quadl * 8 + sub * 2;
            gBf[(kl * 4 + nt) * 256 + lane * 4 + sub] =
                pack2bf(smT[c * 52 + hw], smT[(c + 1) * 52 + hw]);
        }
    } else if (blk < 5440) {
        int X = (blk - 5120) * 256 + tid;          // 0..81919
        int sub = X & 3, lane = (X >> 2) & 63, f = X >> 8;
        int mt = f & 7, K32 = f >> 3;
        int o = mt * 16 + (lane & 15);
        int c = K32 * 32 + (lane >> 4) * 8 + sub * 2;
        float2 v = *(const float2*)(W1 + o * CIN_ + c);
        ws[WS_W1F + X] = pack2bf(v.x, v.y);
    } else {
        int X = (blk - 5440) * 256 + tid;          // 0..5119
        int sub = X & 3, lane = (X >> 2) & 63, f = X >> 8;
        int mt2 = f % 5, ks2 = f / 5;
        int o2 = mt2 * 16 + (lane & 15);
        int c = ks2 * 32 + (lane >> 4) * 8 + sub * 2;
        unsigned val = 0;
        if (o2 < OUTD_) {
            float2 v = *(const float2*)(W2 + o2 * HID_ + c);
            val = pack2bf(v.x, v.y);
        }
        ws[WS_W2F + X] = val;
    }
}

// ---------------------------------------------------------------------------
// Kernel A: block (b, ksp). LDS-free, barrier-free K-loop: 10 steps, each
// 6 coalesced dwordx4 loads (prefetched 1 ahead) + 8 MFMA. Wave w owns
// m-tiles 2w,2w+1; B frags shared by all 4 waves (L1 hits). Then bf16 partial
// store + fused IoU quarter (small LDS for P/G boxes).
// ---------------------------------------------------------------------------
__global__ __launch_bounds__(256) void gemm1_partial(
    const float* __restrict__ grid, const float* __restrict__ bbox,
    const float* __restrict__ anc, const unsigned* __restrict__ ws,
    unsigned* __restrict__ wsp, float* __restrict__ out)
{
    __shared__ float smPG[NP_ * 6 + NGT_ * 5];   // 11,384 B
    float* smP = smPG;
    float* smG = smPG + NP_ * 6;

    const int tid  = threadIdx.x;
    const int b    = blockIdx.x >> 2;
    const int ksp  = blockIdx.x & 3;
    const int lane = tid & 63;
    const int w    = tid >> 6;         // 0..3
    const int quad = lane >> 4;
    const int m16  = lane & 15;

    const int K32b = ksp * 10;
    const uint4* Bp  = (const uint4*)(ws + WS_BF) + b * 10240 + K32b * 256 + lane;
    const uint4* Ap0 = (const uint4*)(ws + WS_W1F) + (K32b * 8 + w * 2) * 64 + lane;
    const uint4* Ap1 = Ap0 + 64;

    f32x4 acc0[4], acc1[4];
    #pragma unroll
    for (int nt = 0; nt < 4; ++nt) { acc0[nt] = (f32x4)(0.f); acc1[nt] = (f32x4)(0.f); }

    uint4 a0 = Ap0[0], a1 = Ap1[0];
    uint4 bv0 = Bp[0], bv1 = Bp[64], bv2 = Bp[128], bv3 = Bp[192];

    for (int k = 0; k < 10; ++k) {
        uint4 na0, na1, nb0, nb1, nb2, nb3;
        if (k < 9) {
            na0 = Ap0[(k + 1) * 512]; na1 = Ap1[(k + 1) * 512];
            const uint4* nBp = Bp + (k + 1) * 256;
            nb0 = nBp[0]; nb1 = nBp[64]; nb2 = nBp[128]; nb3 = nBp[192];
        }
        bf16x8 A0 = as_bf(a0), A1 = as_bf(a1);
        bf16x8 B0 = as_bf(bv0), B1f = as_bf(bv1), B2f = as_bf(bv2), B3 = as_bf(bv3);
        acc0[0] = __builtin_amdgcn_mfma_f32_16x16x32_bf16(A0, B0,  acc0[0], 0, 0, 0);
        acc1[0] = __builtin_amdgcn_mfma_f32_16x16x32_bf16(A1, B0,  acc1[0], 0, 0, 0);
        acc0[1] = __builtin_amdgcn_mfma_f32_16x16x32_bf16(A0, B1f, acc0[1], 0, 0, 0);
        acc1[1] = __builtin_amdgcn_mfma_f32_16x16x32_bf16(A1, B1f, acc1[1], 0, 0, 0);
        acc0[2] = __builtin_amdgcn_mfma_f32_16x16x32_bf16(A0, B2f, acc0[2], 0, 0, 0);
        acc1[2] = __builtin_amdgcn_mfma_f32_16x16x32_bf16(A1, B2f, acc1[2], 0, 0, 0);
        acc0[3] = __builtin_amdgcn_mfma_f32_16x16x32_bf16(A0, B3,  acc0[3], 0, 0, 0);
        acc1[3] = __builtin_amdgcn_mfma_f32_16x16x32_bf16(A1, B3,  acc1[3], 0, 0, 0);
        a0 = na0; a1 = na1;
        bv0 = nb0; bv1 = nb1; bv2 = nb2; bv3 = nb3;
    }

    // ---- store bf16-packed partials: wsp[((b*4+ksp)*64+op)*49+hw] ----
    const unsigned pbase = (unsigned)(b * 4 + ksp) * 64u;
    #pragma unroll
    for (int m = 0; m < 2; ++m) {
        const f32x4* ac = m ? acc1 : acc0;
        int mtg = w * 2 + m;
        #pragma unroll
        for (int nt = 0; nt < 4; ++nt) {
            int hw = (nt < 3) ? (nt * 16 + m16) : ((m16 == 0) ? 48 : -1);
            if (hw >= 0) {
                #pragma unroll
                for (int rp = 0; rp < 2; ++rp) {
                    int op = mtg * 8 + quad * 2 + rp;
                    wsp[(pbase + op) * 49u + hw] =
                        pack2bf(ac[nt][2 * rp], ac[nt][2 * rp + 1]);
                }
            }
        }
    }

    // ---- stage IoU inputs ----
    for (int pp = tid; pp < NP_; pp += 256) {
        int a = pp / 49, r = pp - a * 49;
        float cx = grid[b * 98 + 2 * r], cy = grid[b * 98 + 2 * r + 1];
        float hx = anc[2 * a] * 0.5f,    hy = anc[2 * a + 1] * 0.5f;
        float x1 = cx - hx, y1 = cy - hy, x2 = cx + hx, y2 = cy + hy;
        smP[pp * 6 + 0] = x1; smP[pp * 6 + 1] = y1;
        smP[pp * 6 + 2] = x2; smP[pp * 6 + 3] = y2;
        smP[pp * 6 + 4] = (x2 - x1) * (y2 - y1);
        smP[pp * 6 + 5] = (fminf(fminf(x1, y1), fminf(x2, y2)) > 0.f) ? 1.f : 0.f;
    }
    if (tid < NGT_) {
        int g = tid;
        float x1 = bbox[b * 200 + g * 5 + 0];
        float y1 = bbox[b * 200 + g * 5 + 1];
        float x2 = bbox[b * 200 + g * 5 + 2];
        float y2 = bbox[b * 200 + g * 5 + 3];
        smG[g * 5 + 0] = x1; smG[g * 5 + 1] = y1;
        smG[g * 5 + 2] = x2; smG[g * 5 + 3] = y2;
        smG[g * 5 + 4] = (x2 - x1) * (y2 - y1);
    }
    __syncthreads();

    // ---- IoU quarter ----
    for (int ii = tid; ii < 4410; ii += 256) {
        int idx = ksp * 4410 + ii;
        int p = idx / 40;
        int g = idx - p * 40;
        const float* P = smP + p * 6;
        const float* G = smG + g * 5;
        float tlx = fmaxf(P[0], G[0]);
        float tly = fmaxf(P[1], G[1]);
        float brx = fminf(P[2], G[2]);
        float bry = fminf(P[3], G[3]);
        float dx = fmaxf(brx - tlx, 0.f);
        float dy = fmaxf(bry - tly, 0.f);
        float inter = dx * dy * P[5];
        out[IOU_OFF + b * (NP_ * NGT_) + idx] = inter / (G[4] + P[4] - inter);
    }
}

// ---------------------------------------------------------------------------
// Kernel B: per image. Sum 4 partials + bias + leaky -> smHT [hw][op] stride 68;
// GEMM2 via MFMA; branchy epilogue. 320 threads = 5 waves. (R6, proven.)
// ---------------------------------------------------------------------------
__global__ __launch_bounds__(320) void gemm2_epilogue(
    const unsigned* __restrict__ wsp, const unsigned* __restrict__ gW2f,
    const float* __restrict__ B1, const float* __restrict__ B2,
    float* __restrict__ out)
{
    __shared__ __align__(16) unsigned smHT[49 * 68];   // 13,328 B

    const int tid  = threadIdx.x;
    const int b    = blockIdx.x;
    const int lane = tid & 63;
    const int w    = tid >> 6;         // 0..4 = m-tile
    const int quad = lane >> 4;
    const int m16  = lane & 15;

    const uint4* Aw2 = (const uint4*)gW2f + w * 64 + lane;
    uint4 af0 = Aw2[0], af1 = Aw2[320], af2 = Aw2[640], af3 = Aw2[960];

    const unsigned* pb = wsp + b * 12544;
    for (int j = tid; j < 3136; j += 320) {
        int op = j / 49;
        int hw = j - op * 49;
        const unsigned* p = pb + op * 49 + hw;
        unsigned u0 = p[0], u1 = p[3136], u2 = p[6272], u3 = p[9408];
        float v0 = ((bflo(u0) + bflo(u1)) + (bflo(u2) + bflo(u3))) + B1[2 * op];
        float v1 = ((bfhi(u0) + bfhi(u1)) + (bfhi(u2) + bfhi(u3))) + B1[2 * op + 1];
        v0 = v0 > 0.f ? v0 : 0.01f * v0;
        v1 = v1 > 0.f ? v1 : 0.01f * v1;
        smHT[hw * 68 + op] = pack2bf(v0, v1);
    }
    __syncthreads();

    const int row3 = (m16 == 0) ? 48 : (m16 - 1);
    const unsigned* Bb[4] = {
        smHT + m16 * 68 + quad * 4,
        smHT + (16 + m16) * 68 + quad * 4,
        smHT + (32 + m16) * 68 + quad * 4,
        smHT + row3 * 68 + quad * 4
    };
    f32x4 acc[4];
    #pragma unroll
    for (int nt = 0; nt < 4; ++nt) acc[nt] = (f32x4)(0.f);
    uint4 afs[4] = { af0, af1, af2, af3 };
    #pragma unroll
    for (int ks2 = 0; ks2 < 4; ++ks2) {
        bf16x8 A = as_bf(afs[ks2]);
        const int co = ks2 * 16;
        #pragma unroll
        for (int nt = 0; nt < 4; ++nt) {
            bf16x8 Bf = ld_frag(Bb[nt] + co);
            acc[nt] = __builtin_amdgcn_mfma_f32_16x16x32_bf16(A, Bf, acc[nt], 0, 0, 0);
        }
    }

    #pragma unroll
    for (int nt = 0; nt < 4; ++nt) {
        int hw = (nt < 3) ? (nt * 16 + m16) : ((m16 == 0) ? 48 : -1);
        if (hw < 0) continue;
        #pragma unroll
        for (int r = 0; r < 4; ++r) {
            int o2 = w * 16 + quad * 4 + r;
            if (o2 >= OUTD_) continue;
            float a = acc[nt][r] + B2[o2];
            unsigned dst; float val;
            if (o2 < 36) {
                int an = o2 >> 2, kk = o2 & 3;
                val = (kk < 2) ? (sigmoidf_(a) - 0.5f) : a;
                dst = OFFS_OFF + b * 1764 + an * 196 + kk * 49 + hw;
            } else if (o2 < 45) {
                val = sigmoidf_(a);
                dst = CONF_OFF + b * 441 + (o2 - 36) * 49 + hw;
            } else {
                val = a;
                dst = CLS_OFF + b * 980 + (o2 - 45) * 49 + hw;
            }
            out[dst] = val;
        }
    }
}

// ---------------------------------------------------------------------------
// Mid fallback: R5 fused single kernel + standalone prep_w1f (proven path).
// ---------------------------------------------------------------------------
__global__ __launch_bounds__(256) void prep_w1f(const float* __restrict__ W1,
                                                unsigned* __restrict__ g) {
    int X = blockIdx.x * 256 + threadIdx.x;
    int sub = X & 3, lane = (X >> 2) & 63, f = X >> 8;
    int mt = f & 7, K32 = f >> 3;
    int o = mt * 16 + (lane & 15);
    int c = K32 * 32 + (lane >> 4) * 8 + sub * 2;
    float2 v = *(const float2*)(W1 + o * CIN_ + c);
    g[X] = pack2bf(v.x, v.y);
}

#define SF_STRIDE 644
__global__ __launch_bounds__(512) void fused_single(
    const float* __restrict__ F, const float* __restrict__ grid,
    const float* __restrict__ bbox, const float* __restrict__ anc,
    const unsigned* __restrict__ gW1f, const float* __restrict__ B1,
    const float* __restrict__ W2, const float* __restrict__ B2,
    float* __restrict__ out)
{
    __shared__ __align__(16) unsigned lds[49 * SF_STRIDE];
    unsigned* smF = lds;
    unsigned* smH = lds;
    float* smP = (float*)(lds + 3136);
    float* smG = (float*)(lds + 3136 + 2646);

    const int tid  = threadIdx.x;
    const int b    = blockIdx.x;
    const int lane = tid & 63;
    const int w    = tid >> 6;
    const int quad = lane >> 4;
    const int m16  = lane & 15;
    const float* Fb = F + b * (CIN_ * HW_);

    for (int i = tid; i < 640 * 49; i += 512) {
        int cp = i / 49;
        int hw = i - cp * 49;
        const float* s = Fb + (2 * cp) * HW_ + hw;
        smF[hw * SF_STRIDE + cp] = pack2bf(s[0], s[HW_]);
    }
    __syncthreads();

    const int row3 = (m16 == 0) ? 48 : (m16 - 1);
    const unsigned* Bb[4] = {
        smF + m16 * SF_STRIDE + quad * 4,
        smF + (16 + m16) * SF_STRIDE + quad * 4,
        smF + (32 + m16) * SF_STRIDE + quad * 4,
        smF + row3 * SF_STRIDE + quad * 4
    };
    const uint4* Aw = (const uint4*)gW1f + w * 64 + lane;

    f32x4 acc[4];
    #pragma unroll
    for (int nt = 0; nt < 4; ++nt) acc[nt] = (f32x4)(0.f);

    uint4 a0 = Aw[0], a1 = Aw[512];
    for (int ch = 0; ch < 20; ++ch) {
        uint4 n0, n1;
        if (ch < 19) { n0 = Aw[(ch + 1) * 1024]; n1 = Aw[(ch + 1) * 1024 + 512]; }
        const int coff = ch * 32;
        bf16x8 A0 = as_bf(a0), A1 = as_bf(a1);
        #pragma unroll
        for (int nt = 0; nt < 4; ++nt) {
            bf16x8 b0 = ld_frag(Bb[nt] + coff);
            bf16x8 b1 = ld_frag(Bb[nt] + coff + 16);
            acc[nt] = __builtin_amdgcn_mfma_f32_16x16x32_bf16(A0, b0, acc[nt], 0, 0, 0);
            acc[nt] = __builtin_amdgcn_mfma_f32_16x16x32_bf16(A1, b1, acc[nt], 0, 0, 0);
        }
        a0 = n0; a1 = n1;
    }
    __syncthreads();

    #pragma unroll
    for (int nt = 0; nt < 4; ++nt) {
        int hw = (nt < 3) ? (nt * 16 + m16) : ((m16 == 0) ? 48 : -1);
        if (hw >= 0) {
            #pragma unroll
            for (int rp = 0; rp < 2; ++rp) {
                int o0 = w * 16 + quad * 4 + 2 * rp;
                float v0 = acc[nt][2 * rp]     + B1[o0];
                float v1 = acc[nt][2 * rp + 1] + B1[o0 + 1];
                v0 = v0 > 0.f ? v0 : 0.01f * v0;
                v1 = v1 > 0.f ? v1 : 0.01f * v1;
                smH[(o0 >> 1) * HW_ + hw] = pack2bf(v0, v1);
            }
        }
    }
    if (tid < NP_) {
        int pp = tid, a = pp / 49, r = pp - a * 49;
        float cx = grid[b * 98 + 2 * r], cy = grid[b * 98 + 2 * r + 1];
        float hx = anc[2 * a] * 0.5f,    hy = anc[2 * a + 1] * 0.5f;
        float x1 = cx - hx, y1 = cy - hy, x2 = cx + hx, y2 = cy + hy;
        smP[pp * 6 + 0] = x1; smP[pp * 6 + 1] = y1;
        smP[pp * 6 + 2] = x2; smP[pp * 6 + 3] = y2;
        smP[pp * 6 + 4] = (x2 - x1) * (y2 - y1);
        smP[pp * 6 + 5] = (fminf(fminf(x1, y1), fminf(x2, y2)) > 0.f) ? 1.f : 0.f;
    }
    if (tid >= 472) {
        int g = tid - 472;
        float x1 = bbox[b * 200 + g * 5 + 0];
        float y1 = bbox[b * 200 + g * 5 + 1];
        float x2 = bbox[b * 200 + g * 5 + 2];
        float y2 = bbox[b * 200 + g * 5 + 3];
        smG[g * 5 + 0] = x1; smG[g * 5 + 1] = y1;
        smG[g * 5 + 2] = x2; smG[g * 5 + 3] = y2;
        smG[g * 5 + 4] = (x2 - x1) * (y2 - y1);
    }
    __syncthreads();

    for (int idx = tid; idx < OUTD_ * HW_; idx += 512) {
        int o2 = idx / 49;
        int hw = idx - o2 * 49;
        const float2* wr = (const float2*)(W2 + o2 * HID_);
        float s0 = 0.f, s1 = 0.f;
        #pragma unroll 8
        for (int k2 = 0; k2 < 64; ++k2) {
            unsigned hp = smH[k2 * HW_ + hw];
            float2 wv = wr[k2];
            s0 = fmaf(wv.x, bflo(hp), s0);
            s1 = fmaf(wv.y, bfhi(hp), s1);
        }
        float a = B2[o2] + (s0 + s1);
        unsigned dst; float val;
        if (o2 < 36) {
            int an = o2 >> 2, kk = o2 & 3;
            val = (kk < 2) ? (sigmoidf_(a) - 0.5f) : a;
            dst = OFFS_OFF + b * 1764 + an * 196 + kk * 49 + hw;
        } else if (o2 < 45) {
            val = sigmoidf_(a);
            dst = CONF_OFF + b * 441 + (o2 - 36) * 49 + hw;
        } else {
            val = a;
            dst = CLS_OFF + b * 980 + (o2 - 45) * 49 + hw;
        }
        out[dst] = val;
    }
    for (int idx = tid; idx < NP_ * NGT_; idx += 512) {
        int pp = idx / 40;
        int g  = idx - pp * 40;
        const float* P = smP + pp * 6;
        const float* G = smG + g * 5;
        float tlx = fmaxf(P[0], G[0]);
        float tly = fmaxf(P[1], G[1]);
        float brx = fminf(P[2], G[2]);
        float bry = fminf(P[3], G[3]);
        float dx = fmaxf(brx - tlx, 0.f);
        float dy = fmaxf(bry - tly, 0.f);
        float inter = dx * dy * P[5];
        out[IOU_OFF + b * (NP_ * NGT_) + idx] = inter / (G[4] + P[4] - inter);
    }
}

extern "C" void kernel_launch(void* const* d_in, const int* in_sizes, int n_in,
                              void* d_out, int out_size, void* d_ws, size_t ws_size,
                              hipStream_t stream) {
    const float* F  = (const float*)d_in[0];
    const float* G  = (const float*)d_in[1];
    const float* BB = (const float*)d_in[2];
    const float* AN = (const float*)d_in[3];
    const float* W1 = (const float*)d_in[4];
    const float* B1 = (const float*)d_in[5];
    const float* W2 = (const float*)d_in[6];
    const float* B2 = (const float*)d_in[7];
    float* out = (float*)d_out;
    unsigned* wsu = (unsigned*)d_ws;

    if (ws_size >= (size_t)WS_NEED_FULL) {
        prep_all<<<5460, 256, 0, stream>>>(F, W1, W2, wsu);
        gemm1_partial<<<1024, 256, 0, stream>>>(G, BB, AN, wsu,
                                                wsu + WS_PART, out);
        gemm2_epilogue<<<256, 320, 0, stream>>>(wsu + WS_PART, wsu + WS_W2F,
                                                B1, B2, out);
    } else if (ws_size >= (size_t)WS_NEED_MID) {
        prep_w1f<<<320, 256, 0, stream>>>(W1, wsu + WS_W1F);
        fused_single<<<256, 512, 0, stream>>>(F, G, BB, AN, wsu + WS_W1F,
                                              B1, W2, B2, out);
    } else {
        // ws too small for any prepped path; fused_single needs gW1f, so this
        // config is unsupported — but harness always provides ample ws.
        prep_w1f<<<320, 256, 0, stream>>>(W1, wsu + WS_W1F);
        fused_single<<<256, 512, 0, stream>>>(F, G, BB, AN, wsu + WS_W1F,
                                              B1, W2, B2, out);
    }
}